// Round 6
// baseline (532.903 us; speedup 1.0000x reference)
//
#include <hip/hip_runtime.h>
#include <cstddef>
#include <cstdint>

constexpr int Nf = 128, Pp = 256, Dd = 256, Hh = 16, Mm = 32;
constexpr int OUTC = 512, HID = 2048, C3 = 1536;

typedef short short8 __attribute__((ext_vector_type(8)));   // 8 bf16 (4 VGPRs)
typedef float f32x4 __attribute__((ext_vector_type(4)));    // 4 fp32 acc

// fp32 -> bf16 round-to-nearest-even
__device__ inline unsigned short f2bf(float f) {
  unsigned u = __float_as_uint(f);
  u += 0x7fffu + ((u >> 16) & 1u);
  return (unsigned short)(u >> 16);
}
__device__ inline unsigned pk2(float a, float b) {
  return (unsigned)f2bf(a) | ((unsigned)f2bf(b) << 16);
}

// ---------------------------------------------------------------------------
__global__ __launch_bounds__(256) void conv_x(const float* __restrict__ x,
                                              short* __restrict__ xb) {
  int idx = blockIdx.x * 256 + threadIdx.x;
  const float4* s = (const float4*)x + (size_t)idx * 2;
  float4 a = s[0], c = s[1];
  uint4 o;
  o.x = pk2(a.x, a.y); o.y = pk2(a.z, a.w);
  o.z = pk2(c.x, c.y); o.w = pk2(c.z, c.w);
  ((uint4*)xb)[idx] = o;
}

// Generic coalesced transpose: in (R x C fp32, slice z) -> out (C x R bf16).
__global__ __launch_bounds__(256) void transpose_to_bf16(const float* __restrict__ in,
                                                         short* __restrict__ out,
                                                         int R, int C) {
  __shared__ float tile[64 * 65];
  const int t = threadIdx.x;
  const int rb = blockIdx.y * 64, cb = blockIdx.x * 64;
  const size_t sl = (size_t)blockIdx.z * R * C;
#pragma unroll
  for (int u = 0; u < 4; ++u) {
    int r = (t >> 4) + u * 16, c4 = (t & 15) * 4;
    float4 v = *(const float4*)(in + sl + (size_t)(rb + r) * C + cb + c4);
    tile[r * 65 + c4 + 0] = v.x;
    tile[r * 65 + c4 + 1] = v.y;
    tile[r * 65 + c4 + 2] = v.z;
    tile[r * 65 + c4 + 3] = v.w;
  }
  __syncthreads();
#pragma unroll
  for (int u = 0; u < 2; ++u) {
    int id = t + u * 256;
    int n = id >> 3, kg = id & 7;
    float a[8];
#pragma unroll
    for (int q = 0; q < 8; ++q) a[q] = tile[(kg * 8 + q) * 65 + n];
    uint4 o;
    o.x = pk2(a[0], a[1]); o.y = pk2(a[2], a[3]);
    o.z = pk2(a[4], a[5]); o.w = pk2(a[6], a[7]);
    *(uint4*)(out + sl + (size_t)(cb + n) * R + rb + kg * 8) = o;
  }
}

// B2t[c][k], k = HH*32+MM (1536 x 512) — reads are 128B runs, already coalesced.
__global__ void repack_b2t(const float* __restrict__ Wp, short* __restrict__ B2t) {
  int idx = blockIdx.x * 256 + threadIdx.x;  // 786432
  int c = idx >> 9, k = idx & 511;
  int w = c >> 9, h = (c >> 5) & 15, m = c & 31;
  int HH = k >> 5, MM = k & 31;
  B2t[idx] = (short)f2bf(Wp[(((w * Hh + h) * Mm + m) * Hh + HH) * Mm + MM]);
}

// ---------------------------------------------------------------------------
// bf16 MFMA GEMM: 128x128 tile, BK=64 (half the barriers of m97's BK=32),
// XOR-swizzled LDS (16B segment kg stored at (kg+row)&7, realized by permuting
// the GLOBAL source address per lane; fragment reads apply the same rotation)
// so ds_read_b128 lanes spread across all 32 banks. XCD-aware block swizzle
// keeps col-blocks sharing an A row-panel on one XCD (L2 reuse).
template <int KDIM, int NCOLS, int AMAP, int EPI, int OUTT>
__global__ __launch_bounds__(256) void gemm_mfma(const short* __restrict__ A,
                                                 const short* __restrict__ Bt,
                                                 void* __restrict__ Cv,
                                                 const float* __restrict__ bias,
                                                 int j0, int pshift, int pc) {
  __shared__ short As[128 * 64];   // 16 KB, [row][8 segs of 8 shorts, rotated]
  __shared__ short Bs[128 * 64];   // 16 KB
  const int t = threadIdx.x;
  const int wv = t >> 6, ln = t & 63;
  const int wr = wv >> 1, wc = wv & 1;
  const int lr = ln & 15, kq = ln >> 4;

  constexpr int NBX = NCOLS / 128;
  int lin = blockIdx.y * NBX + blockIdx.x;
  int nblk = gridDim.x * gridDim.y;
  int bx, by;
  if ((nblk & 7) == 0) {
    int per = nblk >> 3;
    int id = (lin & 7) * per + (lin >> 3);   // bijective; groups rows per XCD
    bx = id % NBX; by = id / NBX;
  } else {
    bx = blockIdx.x; by = blockIdx.y;
  }
  const int row0 = by * 128, col0 = bx * 128;

  f32x4 acc[4][4];
#pragma unroll
  for (int i = 0; i < 4; ++i)
#pragma unroll
    for (int j = 0; j < 4; ++j) acc[i][j] = {0.f, 0.f, 0.f, 0.f};

  for (int kt = 0; kt < KDIM; kt += 64) {
    // stage A: 1024 16B slots; slot s -> row=s>>3, LDS seg s&7 holds global
    // seg kg = (s&7 - row)&7 (the XOR/rotate swizzle).
#pragma unroll
    for (int u = 0; u < 4; ++u) {
      int s = wv * 256 + u * 64 + ln;
      int r = s >> 3;
      int kg = ((s & 7) - r) & 7;
      int rr = row0 + r;
      size_t arow;
      if (AMAP == 0) arow = (size_t)rr;
      else { int i = rr >> pshift, jj = rr & (pc - 1); arow = (size_t)((i << 8) + j0 + jj); }
      const short* gp = A + arow * KDIM + kt + kg * 8;
      __builtin_amdgcn_global_load_lds(
          (const __attribute__((address_space(1))) void*)gp,
          (__attribute__((address_space(3))) void*)&As[(wv * 256 + u * 64) * 8], 16, 0, 0);
    }
#pragma unroll
    for (int u = 0; u < 4; ++u) {
      int s = wv * 256 + u * 64 + ln;
      int r = s >> 3;
      int kg = ((s & 7) - r) & 7;
      const short* gp = Bt + (size_t)(col0 + r) * KDIM + kt + kg * 8;
      __builtin_amdgcn_global_load_lds(
          (const __attribute__((address_space(1))) void*)gp,
          (__attribute__((address_space(3))) void*)&Bs[(wv * 256 + u * 64) * 8], 16, 0, 0);
    }
    __syncthreads();
#pragma unroll
    for (int ks = 0; ks < 2; ++ks) {
      short8 a[4], b[4];
#pragma unroll
      for (int ti = 0; ti < 4; ++ti) {
        int row = wr * 64 + ti * 16 + lr;
        int seg = (ks * 4 + kq + row) & 7;
        a[ti] = *(const short8*)&As[row * 64 + seg * 8];
      }
#pragma unroll
      for (int tj = 0; tj < 4; ++tj) {
        int row = wc * 64 + tj * 16 + lr;
        int seg = (ks * 4 + kq + row) & 7;
        b[tj] = *(const short8*)&Bs[row * 64 + seg * 8];
      }
#pragma unroll
      for (int ti = 0; ti < 4; ++ti)
#pragma unroll
        for (int tj = 0; tj < 4; ++tj)
          acc[ti][tj] = __builtin_amdgcn_mfma_f32_16x16x32_bf16(a[ti], b[tj], acc[ti][tj], 0, 0, 0);
    }
    __syncthreads();
  }

#pragma unroll
  for (int tj = 0; tj < 4; ++tj) {
    int gcol = col0 + wc * 64 + tj * 16 + lr;
    float bv = (EPI == 0) ? bias[gcol] : 0.f;
#pragma unroll
    for (int ti = 0; ti < 4; ++ti) {
#pragma unroll
      for (int rg = 0; rg < 4; ++rg) {
        int grow = row0 + wr * 64 + ti * 16 + kq * 4 + rg;
        float val = acc[ti][tj][rg];
        if (EPI == 0) {
          val += bv;
          if (OUTT == 0) ((short*)Cv)[(size_t)grow * NCOLS + gcol] = (short)f2bf(val);
          else           ((float*)Cv)[(size_t)grow * NCOLS + gcol] = val;
        } else {
          int w = gcol >> 9, h = (gcol >> 5) & 15, m = gcol & 31;
          size_t addr;
          if (EPI == 1) {
            int i = grow >> pshift, jj = grow & (pc - 1);
            addr = (((size_t)(w * Hh + h) * pc + jj) * Nf + i) * Mm + m;
          } else {
            int ii = grow >> 8, j = grow & 255;
            addr = (((size_t)(w * Hh + h) * pc + ii) * Pp + j) * Mm + m;
          }
          ((short*)Cv)[addr] = (short)f2bf(val);
        }
      }
    }
  }
}

// ---------------------------------------------------------------------------
// Temporal attention, MFMA (unchanged — verified).
__global__ __launch_bounds__(256) void temporal_attn_mfma(const short* __restrict__ T,
                                                          short* __restrict__ At,
                                                          int j0, int jcShift) {
  constexpr int QsO = 0, KsO = 4096, VtO = 8192, WtO = 12544, RsO = 29952;
  __shared__ __align__(16) short lds[30464];
  float* rs = (float*)&lds[RsO];
  const int JC = 1 << jcShift;
  const int h  = blockIdx.x >> jcShift;
  const int jj = blockIdx.x & (JC - 1);
  const int t  = threadIdx.x;
  const int wv = t >> 6, ln = t & 63;
  const int wr = wv >> 1, wc = wv & 1;
  const int lr = ln & 15, kq = ln >> 4;
  const size_t WC = (size_t)(Hh << jcShift) * 4096;
  const short* qb = T + (size_t)(h * JC + jj) * 4096;
  const short* kb = qb + WC;
  const short* vb = qb + 2 * WC;

#pragma unroll
  for (int u = 0; u < 2; ++u) {
    int seg = wv * 2 + u;
    __builtin_amdgcn_global_load_lds(
        (const __attribute__((address_space(1))) void*)(qb + seg * 512 + ln * 8),
        (__attribute__((address_space(3))) void*)&lds[QsO + seg * 512], 16, 0, 0);
    __builtin_amdgcn_global_load_lds(
        (const __attribute__((address_space(1))) void*)(kb + seg * 512 + ln * 8),
        (__attribute__((address_space(3))) void*)&lds[KsO + seg * 512], 16, 0, 0);
  }
#pragma unroll
  for (int u = 0; u < 2; ++u) {
    int idx = t + u * 256;
    int I = idx >> 2, m0 = (idx & 3) * 8;
    uint4 v = *(const uint4*)(vb + idx * 8);
    const short* vs = (const short*)&v;
#pragma unroll
    for (int q = 0; q < 8; ++q) lds[VtO + (m0 + q) * 136 + I] = vs[q];
  }
  __syncthreads();

  short8 af[4], bf[4];
#pragma unroll
  for (int ti = 0; ti < 4; ++ti)
    af[ti] = *(const short8*)&lds[QsO + (wr * 64 + ti * 16 + lr) * 32 + kq * 8];
#pragma unroll
  for (int tj = 0; tj < 4; ++tj)
    bf[tj] = *(const short8*)&lds[KsO + (wc * 64 + tj * 16 + lr) * 32 + kq * 8];
  f32x4 e[4][4];
#pragma unroll
  for (int ti = 0; ti < 4; ++ti)
#pragma unroll
    for (int tj = 0; tj < 4; ++tj) e[ti][tj] = {0.f, 0.f, 0.f, 0.f};
#pragma unroll
  for (int ti = 0; ti < 4; ++ti)
#pragma unroll
    for (int tj = 0; tj < 4; ++tj)
      e[ti][tj] = __builtin_amdgcn_mfma_f32_16x16x32_bf16(af[ti], bf[tj], e[ti][tj], 0, 0, 0);

  float part[4][4];
#pragma unroll
  for (int ti = 0; ti < 4; ++ti)
#pragma unroll
    for (int r = 0; r < 4; ++r) {
      float p = 0.f;
#pragma unroll
      for (int tj = 0; tj < 4; ++tj) {
        float ex = __expf(e[ti][tj][r]);
        e[ti][tj][r] = ex;
        p += ex;
      }
      part[ti][r] = p;
    }
#pragma unroll
  for (int msk = 1; msk <= 8; msk <<= 1)
#pragma unroll
    for (int ti = 0; ti < 4; ++ti)
#pragma unroll
      for (int r = 0; r < 4; ++r)
        part[ti][r] += __shfl_xor(part[ti][r], msk, 64);
  if (lr == 0) {
#pragma unroll
    for (int ti = 0; ti < 4; ++ti)
#pragma unroll
      for (int r = 0; r < 4; ++r)
        rs[wc * 128 + wr * 64 + ti * 16 + kq * 4 + r] = part[ti][r];
  }
  __syncthreads();

#pragma unroll
  for (int ti = 0; ti < 4; ++ti) {
#pragma unroll
    for (int r = 0; r < 4; ++r) {
      int I = wr * 64 + ti * 16 + kq * 4 + r;
      float inv = 1.f / (rs[I] + rs[128 + I]);
#pragma unroll
      for (int tj = 0; tj < 4; ++tj) e[ti][tj][r] *= inv;
    }
#pragma unroll
    for (int tj = 0; tj < 4; ++tj) {
      int i = wc * 64 + tj * 16 + lr;
      int Ib = wr * 64 + ti * 16 + kq * 4;
      uint2 pk;
      pk.x = pk2(e[ti][tj][0], e[ti][tj][1]);
      pk.y = pk2(e[ti][tj][2], e[ti][tj][3]);
      *(uint2*)&lds[WtO + i * 136 + Ib] = pk;
    }
  }
  __syncthreads();

  f32x4 o[2][2];
#pragma unroll
  for (int tr = 0; tr < 2; ++tr)
#pragma unroll
    for (int tm = 0; tm < 2; ++tm) o[tr][tm] = {0.f, 0.f, 0.f, 0.f};
#pragma unroll
  for (int ks = 0; ks < 4; ++ks) {
    short8 ea[2], vf[2];
#pragma unroll
    for (int tr = 0; tr < 2; ++tr)
      ea[tr] = *(const short8*)&lds[WtO + (wv * 32 + tr * 16 + lr) * 136 + ks * 32 + kq * 8];
#pragma unroll
    for (int tm = 0; tm < 2; ++tm)
      vf[tm] = *(const short8*)&lds[VtO + (tm * 16 + lr) * 136 + ks * 32 + kq * 8];
#pragma unroll
    for (int tr = 0; tr < 2; ++tr)
#pragma unroll
      for (int tm = 0; tm < 2; ++tm)
        o[tr][tm] = __builtin_amdgcn_mfma_f32_16x16x32_bf16(ea[tr], vf[tm], o[tr][tm], 0, 0, 0);
  }
#pragma unroll
  for (int tr = 0; tr < 2; ++tr)
#pragma unroll
    for (int tm = 0; tm < 2; ++tm)
#pragma unroll
      for (int r = 0; r < 4; ++r) {
        int row = wv * 32 + tr * 16 + kq * 4 + r;
        lds[row * 40 + tm * 16 + lr] = (short)f2bf(o[tr][tm][r]);
      }
  __syncthreads();
#pragma unroll
  for (int u = 0; u < 2; ++u) {
    int idx = t + u * 256;
    int i = idx >> 2, mg = idx & 3;
    uint4 vv = *(const uint4*)&lds[i * 40 + mg * 8];
    *(uint4*)(At + ((size_t)(i * Pp + j0 + jj) * OUTC + h * 32 + mg * 8)) = vv;
  }
}

// ---------------------------------------------------------------------------
// Point attention, MFMA (unchanged — verified).
__global__ __launch_bounds__(256) void point_attn_mfma(const short* __restrict__ P,
                                                       short* __restrict__ PA,
                                                       int icShift) {
  constexpr int QsO = 0, KsO = 4096, VtO = 8192, EO = 12544, CsO = 29952;
  __shared__ __align__(16) short lds[30720];
  float* cs    = (float*)&lds[CsO];
  float* denom = cs + 256;
  const int IC = 1 << icShift;
  const int bx = blockIdx.x;
  const int h    = bx >> (icShift + 1);
  const int rem  = bx & ((IC << 1) - 1);
  const int ii   = rem >> 1;
  const int half = rem & 1;
  const int t  = threadIdx.x;
  const int wv = t >> 6, ln = t & 63;
  const int wr = wv >> 1, wc = wv & 1;
  const int lr = ln & 15, kq = ln >> 4;
  const size_t WC = (size_t)(Hh << icShift) * 8192;
  const short* qb = P + (size_t)(h * IC + ii) * 8192 + half * 4096;
  const short* kb = P + WC + (size_t)(h * IC + ii) * 8192;
  const short* vb = kb + WC;

  f32x4 o[2][2];
#pragma unroll
  for (int tr = 0; tr < 2; ++tr)
#pragma unroll
    for (int tm = 0; tm < 2; ++tm) o[tr][tm] = {0.f, 0.f, 0.f, 0.f};

  for (int chunk = 0; chunk < 2; ++chunk) {
    const int Jb = chunk * 128;
    if (chunk) __syncthreads();
#pragma unroll
    for (int u = 0; u < 2; ++u) {
      int seg = wv * 2 + u;
      __builtin_amdgcn_global_load_lds(
          (const __attribute__((address_space(1))) void*)(kb + Jb * 32 + seg * 512 + ln * 8),
          (__attribute__((address_space(3))) void*)&lds[KsO + seg * 512], 16, 0, 0);
    }
    if (chunk == 0) {
#pragma unroll
      for (int u = 0; u < 2; ++u) {
        int seg = wv * 2 + u;
        __builtin_amdgcn_global_load_lds(
            (const __attribute__((address_space(1))) void*)(qb + seg * 512 + ln * 8),
            (__attribute__((address_space(3))) void*)&lds[QsO + seg * 512], 16, 0, 0);
      }
      if (t < 128) denom[t] = 0.f;
    }
#pragma unroll
    for (int u = 0; u < 2; ++u) {
      int idx = t + u * 256;
      int Jl = idx >> 2, m0 = (idx & 3) * 8;
      uint4 v = *(const uint4*)(vb + Jb * 32 + idx * 8);
      const short* vs = (const short*)&v;
#pragma unroll
      for (int q = 0; q < 8; ++q) lds[VtO + (m0 + q) * 136 + Jl] = vs[q];
    }
    __syncthreads();

    short8 af[4], bf[4];
#pragma unroll
    for (int ti = 0; ti < 4; ++ti)
      af[ti] = *(const short8*)&lds[KsO + (wr * 64 + ti * 16 + lr) * 32 + kq * 8];
#pragma unroll
    for (int tj = 0; tj < 4; ++tj)
      bf[tj] = *(const short8*)&lds[QsO + (wc * 64 + tj * 16 + lr) * 32 + kq * 8];
    f32x4 e[4][4];
#pragma unroll
    for (int ti = 0; ti < 4; ++ti)
#pragma unroll
      for (int tj = 0; tj < 4; ++tj) e[ti][tj] = {0.f, 0.f, 0.f, 0.f};
#pragma unroll
    for (int ti = 0; ti < 4; ++ti)
#pragma unroll
      for (int tj = 0; tj < 4; ++tj)
        e[ti][tj] = __builtin_amdgcn_mfma_f32_16x16x32_bf16(af[ti], bf[tj], e[ti][tj], 0, 0, 0);

    float cp[4] = {0.f, 0.f, 0.f, 0.f};
#pragma unroll
    for (int ti = 0; ti < 4; ++ti)
#pragma unroll
      for (int tj = 0; tj < 4; ++tj)
#pragma unroll
        for (int r = 0; r < 4; ++r) {
          float ex = __expf(e[ti][tj][r]);
          e[ti][tj][r] = ex;
          cp[tj] += ex;
        }
#pragma unroll
    for (int tj = 0; tj < 4; ++tj) {
      cp[tj] += __shfl_xor(cp[tj], 16, 64);
      cp[tj] += __shfl_xor(cp[tj], 32, 64);
    }
    if (kq == 0) {
#pragma unroll
      for (int tj = 0; tj < 4; ++tj)
        cs[wr * 128 + wc * 64 + tj * 16 + lr] = cp[tj];
    }
#pragma unroll
    for (int ti = 0; ti < 4; ++ti)
#pragma unroll
      for (int tj = 0; tj < 4; ++tj) {
        int j  = wc * 64 + tj * 16 + lr;
        int Jl = wr * 64 + ti * 16 + kq * 4;
        uint2 pk;
        pk.x = pk2(e[ti][tj][0], e[ti][tj][1]);
        pk.y = pk2(e[ti][tj][2], e[ti][tj][3]);
        *(uint2*)&lds[EO + j * 136 + Jl] = pk;
      }
    __syncthreads();
    if (t < 128) denom[t] += cs[t] + cs[128 + t];

#pragma unroll
    for (int ks = 0; ks < 4; ++ks) {
      short8 ea[2], vf[2];
#pragma unroll
      for (int tr = 0; tr < 2; ++tr)
        ea[tr] = *(const short8*)&lds[EO + (wv * 32 + tr * 16 + lr) * 136 + ks * 32 + kq * 8];
#pragma unroll
      for (int tm = 0; tm < 2; ++tm)
        vf[tm] = *(const short8*)&lds[VtO + (tm * 16 + lr) * 136 + ks * 32 + kq * 8];
#pragma unroll
      for (int tr = 0; tr < 2; ++tr)
#pragma unroll
        for (int tm = 0; tm < 2; ++tm)
          o[tr][tm] = __builtin_amdgcn_mfma_f32_16x16x32_bf16(ea[tr], vf[tm], o[tr][tm], 0, 0, 0);
    }
  }
  __syncthreads();

#pragma unroll
  for (int tr = 0; tr < 2; ++tr)
#pragma unroll
    for (int r = 0; r < 4; ++r) {
      int row = wv * 32 + tr * 16 + kq * 4 + r;
      float rinv = 1.f / denom[row];
#pragma unroll
      for (int tm = 0; tm < 2; ++tm)
        lds[row * 40 + tm * 16 + lr] = (short)f2bf(o[tr][tm][r] * rinv);
    }
  __syncthreads();
#pragma unroll
  for (int u = 0; u < 2; ++u) {
    int idx = t + u * 256;
    int jl = idx >> 2, mg = idx & 3;
    uint4 vv = *(const uint4*)&lds[jl * 40 + mg * 8];
    *(uint4*)(PA + ((size_t)(ii * Pp + half * 128 + jl) * OUTC + h * 32 + mg * 8)) = vv;
  }
}

// ---------------------------------------------------------------------------
extern "C" void kernel_launch(void* const* d_in, const int* in_sizes, int n_in,
                              void* d_out, int out_size, void* d_ws, size_t ws_size,
                              hipStream_t stream) {
  const float* x  = (const float*)d_in[0];
  const float* Wt = (const float*)d_in[1];
  const float* Wp = (const float*)d_in[2];
  const float* W1 = (const float*)d_in[3];
  const float* b1 = (const float*)d_in[4];
  const float* W2 = (const float*)d_in[5];
  const float* b2 = (const float*)d_in[6];
  float* out = (float*)d_out;
  short* ws  = (short*)d_ws;

  const size_t fixedH = 8388608 + 16777216 + 393216 + 786432 + 1048576 + 1048576;
  size_t availH = ws_size / 2;
  size_t chF; int RM, JC, IC;
  if      (availH >= fixedH + 67108864) { chF = 67108864; RM = 32768; JC = 256; IC = 128; }
  else if (availH >= fixedH + 16777216) { chF = 16777216; RM = 8192;  JC = 64;  IC = 32;  }
  else if (availH >= fixedH + 8388608)  { chF = 8388608;  RM = 4096;  JC = 32;  IC = 16;  }
  else                                  { chF = 4194304;  RM = 2048;  JC = 16;  IC = 8;   }
  short* CH  = ws;
  short* xbf = CH + chF;
  short* At  = xbf + 8388608;
  short* B1t = At + 16777216;
  short* B2t = B1t + 393216;
  short* W1t = B2t + 786432;
  short* W2t = W1t + 1048576;
  const int jcS = __builtin_ctz((unsigned)JC);
  const int icS = __builtin_ctz((unsigned)IC);

  conv_x<<<4096, 256, 0, stream>>>(x, xbf);
  transpose_to_bf16<<<dim3(8, 4, 3), 256, 0, stream>>>(Wt, B1t, 256, 512);
  repack_b2t<<<3072, 256, 0, stream>>>(Wp, B2t);
  transpose_to_bf16<<<dim3(32, 8, 1), 256, 0, stream>>>(W1, W1t, 512, 2048);
  transpose_to_bf16<<<dim3(8, 32, 1), 256, 0, stream>>>(W2, W2t, 2048, 512);

  if (JC == 256) {
    gemm_mfma<256, 1536, 0, 1, 0><<<dim3(12, 256), 256, 0, stream>>>(xbf, B1t, CH, nullptr, 0, 8, 256);
    temporal_attn_mfma<<<Hh * 256, 256, 0, stream>>>(CH, At, 0, 8);
    gemm_mfma<512, 1536, 0, 2, 0><<<dim3(12, 256), 256, 0, stream>>>(At, B2t, CH, nullptr, 0, 0, 128);
    point_attn_mfma<<<Hh * 128 * 2, 256, 0, stream>>>(CH, At, 7);
    gemm_mfma<512, 2048, 0, 0, 0><<<dim3(16, 256), 256, 0, stream>>>(At, W1t, CH, b1, 0, 0, 0);
    gemm_mfma<2048, 512, 0, 0, 1><<<dim3(4, 256), 256, 0, stream>>>(CH, W2t, out, b2, 0, 0, 0);
  } else {
    for (int j0 = 0; j0 < Pp; j0 += JC) {
      gemm_mfma<256, 1536, 1, 1, 0><<<dim3(12, JC), 256, 0, stream>>>(xbf, B1t, CH, nullptr, j0, jcS, JC);
      temporal_attn_mfma<<<Hh * JC, 256, 0, stream>>>(CH, At, j0, jcS);
    }
    for (int i0 = 0; i0 < Nf; i0 += IC) {
      short* Arows = At + (size_t)i0 * Pp * OUTC;
      gemm_mfma<512, 1536, 0, 2, 0><<<dim3(12, IC * 2), 256, 0, stream>>>(Arows, B2t, CH, nullptr, 0, 0, IC);
      point_attn_mfma<<<Hh * IC * 2, 256, 0, stream>>>(CH, Arows, icS);
    }
    for (int r0 = 0; r0 < Nf * Pp; r0 += RM) {
      gemm_mfma<512, 2048, 0, 0, 0><<<dim3(16, RM / 128), 256, 0, stream>>>(At + (size_t)r0 * OUTC, W1t, CH, b1, 0, 0, 0);
      gemm_mfma<2048, 512, 0, 0, 1><<<dim3(4, RM / 128), 256, 0, stream>>>(CH, W2t, out + (size_t)r0 * OUTC, b2, 0, 0, 0);
    }
  }
}